// Round 10
// baseline (103.201 us; speedup 1.0000x reference)
//
#include <hip/hip_runtime.h>
#include <float.h>

// CropRoi, separable max-pool: w-pool fused into staging, LDS holds the
// w-pooled tensor t1[d][h][k] (channel-interleaved float4), phase 2 pools
// d/h with 9 ds_read_b128 per output (was 27).
//
// Domain: sides in [8,48] => crop length L <= 13 => every adaptive segment
// has length 1..3, elements {g0, min(g0+1,g1-1), g1-1} (duplicates are
// idempotent under max).
//
// Staging: one thread per (d,h,k) item (Vt = Ld*Lh*7 <= 1183): 3 w-elements
// x 4 channels = 12 independent global dword loads -> fmax -> one
// ds_write_b128. Duplicate w reads hit L1; total fetch unchanged.
// LDS 1183*16 = 18.9 KB -> ~5 blocks/CU @ 384 threads (phase 2 single-pass).

#define NTHREADS 384
#define NCH 4
#define MAXL 13
#define MAXT (MAXL * MAXL * 7)  // 1183
#define BATCH 4                  // ceil(1183/384)

__global__ __launch_bounds__(NTHREADS) void crop_roi_v9(
        const float* __restrict__ f,
        const float* __restrict__ props,
        float* __restrict__ out,
        int C) {
    __shared__ float4 t1[MAXT];  // 18.9 KB, w-pooled, channel-interleaved
    const int cbase = blockIdx.x * NCH;
    const int n = blockIdx.y;
    const int tid = threadIdx.x;

    const float* p = props + (size_t)n * 8;
    const int b = (int)p[0];

    // Bounds: float math matches JAX f32 exactly (exact *0.5, *0.25).
    int d0 = (int)floorf((p[2] - p[5] * 0.5f) * 0.25f);
    int d1 = (int)ceilf ((p[2] + p[5] * 0.5f) * 0.25f);
    int h0 = (int)floorf((p[3] - p[6] * 0.5f) * 0.25f);
    int h1 = (int)ceilf ((p[3] + p[6] * 0.5f) * 0.25f);
    int w0 = (int)floorf((p[4] - p[7] * 0.5f) * 0.25f);
    int w1 = (int)ceilf ((p[4] + p[7] * 0.5f) * 0.25f);
    d0 = max(d0, 0); d1 = min(d1, 32);
    h0 = max(h0, 0); h1 = min(h1, 32);
    w0 = max(w0, 0); w1 = min(w1, 32);
    const int Ld = d1 - d0, Lh = h1 - h0, Lw = w1 - w0;

    const float* base0 = f + (((size_t)b * C + cbase) << 15);  // 32^3
    const int nch = min(NCH, C - cbase);

    size_t choff[NCH];
#pragma unroll
    for (int cs = 0; cs < NCH; ++cs)
        choff[cs] = (size_t)min(cs, nch - 1) << 15;

    if (Ld >= 1 && Ld <= MAXL && Lh >= 1 && Lh <= MAXL && Lw >= 1 && Lw <= MAXL) {
        const int Vt = Ld * Lh * 7;  // items in w-pooled tensor (block-uniform)
        // runtime magic for /Lh (q <= 169 < 2^12 -> exact)
        const unsigned Mh = (Lh > 1) ? (unsigned)(0x100000000ULL / (unsigned)Lh) + 1u : 0u;

        // Phase 1: w-pool fused staging. One (d,h,k) item per thread.
#pragma unroll
        for (int u = 0; u < BATCH; ++u) {
            const int e = tid + u * NTHREADS;
            if (e < Vt) {  // Vt block-uniform -> divergent only at boundary
                const int k = e % 7;            // const divide -> magic
                const int q = e / 7;            // q < 169*... fits
                const int h = (Lh > 1) ? (q - (int)__umulhi((unsigned)q, Mh) * Lh) : 0;
                const int d = (Lh > 1) ? (int)__umulhi((unsigned)q, Mh) : q;
                // w-segment for output k: [g0, g1), length 1..3
                const int g0 = (k * Lw) / 7;
                const int g1 = ((k + 1) * Lw + 6) / 7;
                const int wA = g0, wB = min(g0 + 1, g1 - 1), wC = g1 - 1;
                const int gb = ((((d0 + d) << 5) + (h0 + h)) << 5) + w0;
                float mx[NCH];
#pragma unroll
                for (int cs = 0; cs < NCH; ++cs) {
                    const float* bc = base0 + choff[cs] + gb;
                    const float vA = bc[wA];
                    const float vB = bc[wB];
                    const float vC = bc[wC];
                    mx[cs] = fmaxf(fmaxf(vA, vB), vC);
                }
                t1[e] = make_float4(mx[0], mx[1], mx[2], mx[3]);
            }
        }
        __syncthreads();

        // Phase 2: pool d,h — 3x3 clamped window, 9 ds_read_b128, k fixed.
        if (tid < 343) {
            const int o = tid;
            const int i = o / 49;
            const int j = (o / 7) % 7;
            const int k = o % 7;
            const int a0 = (i * Ld) / 7,  a1 = ((i + 1) * Ld + 6) / 7;
            const int b0 = (j * Lh) / 7,  b1 = ((j + 1) * Lh + 6) / 7;
            const int dd[3] = { a0, min(a0 + 1, a1 - 1), a1 - 1 };
            const int hh[3] = { b0, min(b0 + 1, b1 - 1), b1 - 1 };
            float m0 = -FLT_MAX, m1 = -FLT_MAX, m2 = -FLT_MAX, m3 = -FLT_MAX;
#pragma unroll
            for (int x = 0; x < 3; ++x) {
#pragma unroll
                for (int y = 0; y < 3; ++y) {
                    const float4 v = t1[(dd[x] * Lh + hh[y]) * 7 + k];
                    m0 = fmaxf(m0, v.x);
                    m1 = fmaxf(m1, v.y);
                    m2 = fmaxf(m2, v.z);
                    m3 = fmaxf(m3, v.w);
                }
            }
            const float mm[NCH] = { m0, m1, m2, m3 };
            for (int cs = 0; cs < nch; ++cs)
                out[((size_t)n * C + cbase + cs) * 343 + o] = mm[cs];
        }
    } else {
        // Robust fallback (not taken for harness inputs): direct from global.
        for (int o = tid; o < 343; o += NTHREADS) {
            const int i = o / 49, j = (o / 7) % 7, k = o % 7;
            const int ds = d0 + (i * Ld) / 7, de = d0 + ((i + 1) * Ld + 6) / 7;
            const int hs = h0 + (j * Lh) / 7, he = h0 + ((j + 1) * Lh + 6) / 7;
            const int ws = w0 + (k * Lw) / 7, we = w0 + ((k + 1) * Lw + 6) / 7;
            for (int cs = 0; cs < nch; ++cs) {
                float m = -FLT_MAX;
                const float* basec = base0 + ((size_t)cs << 15);
                for (int d = ds; d < de; ++d)
                    for (int h = hs; h < he; ++h) {
                        const float* row = basec + (d << 10) + (h << 5);
                        for (int w = ws; w < we; ++w) m = fmaxf(m, row[w]);
                    }
                out[((size_t)n * C + cbase + cs) * 343 + o] = m;
            }
        }
    }
}

extern "C" void kernel_launch(void* const* d_in, const int* in_sizes, int n_in,
                              void* d_out, int out_size, void* d_ws, size_t ws_size,
                              hipStream_t stream) {
    const float* f = (const float*)d_in[0];
    const float* props = (const float*)d_in[2];

    int N = in_sizes[2] / 8;       // proposals are (N, 8)
    int C = out_size / (N * 343);  // outputs are (N, C, 7, 7, 7)

    dim3 block(NTHREADS);
    dim3 grid((C + NCH - 1) / NCH, N);
    crop_roi_v9<<<grid, block, 0, stream>>>(f, props, (float*)d_out, C);
}